// Round 7
// baseline (308.470 us; speedup 1.0000x reference)
//
#include <hip/hip_runtime.h>

// Hydra_56633438765296: two-head LoLa/CoLa jet network, fp32 (no fp32 MFMA on CDNA4;
// rank-sensitive top-6 between heads keeps everything fp32 vector math).
// R6 post-mortem: FC2 partial loop was `for(o=w; o+=4)` -- each wave only wrote 1/4
// of its partial slots; the reduce summed stale LDS (absmax 8097). Fix: every wave
// computes its 50-neuron partial for ALL outputs. Structure otherwise identical:
// lane=row, wave=neuron-slice; weights on the scalar pipe (uniform s_load),
// features VGPR-resident (R5 was LDS-BW-bound at 36% VALUBusy).

#define BATCH 32768
#define NJ 10
#define FFDIM 200
#define OUTSTRIDE 21
#define NFEATBLK 4096

typedef float v2f __attribute__((ext_vector_type(2)));

// ---------------- features kernel: cola + lola + BN partials ----------------
template<int NIN, int NP>
__global__ __launch_bounds__(256) void feat_kernel(
    const float* __restrict__ vin,    // [B][NIN][4]
    const float* __restrict__ cola,   // [22][NIN]
    const float* __restrict__ we,     // [NP][NP]
    const float* __restrict__ wd,     // [NP][NP]
    float* __restrict__ fout,         // [B][F] row-major
    float* __restrict__ psum,         // [F][4096]
    float* __restrict__ psq)          // [F][4096]
{
    constexpr int NC = 22;
    constexpr int F  = NP * 5;
    constexpr int RB = 8;             // rows per block
    constexpr int SW = NP + 1;        // odd stride -> conflict-free i-indexed reads
    constexpr int SF = F + 8;         // 2-way max on transposed readout
    __shared__ float s_cola[NC * NIN];
    __shared__ float s_we[NP * SW];
    __shared__ float s_wd[NP * SW];
    __shared__ float4 s_x[RB][NP];
    __shared__ float s_m2[RB][NP];
    __shared__ float s_f[RB * SF];

    const int tid = threadIdx.x;
    const int blk = blockIdx.x;

    for (int k = tid; k < NC * NIN; k += 256) s_cola[k] = cola[k];
    for (int k = tid; k < NP * NP; k += 256) {
        const int i2 = k / NP, j2 = k - i2 * NP;
        s_we[i2 * SW + j2] = we[k];
        s_wd[i2 * SW + j2] = wd[k];
    }
    for (int k = tid; k < RB * NIN * 4; k += 256)
        ((float*)&s_x[0][0])[(k / (NIN * 4)) * NP * 4 + (k % (NIN * 4))] =
            vin[(size_t)blk * RB * NIN * 4 + k];
    __syncthreads();

    const int r = tid >> 5;          // row in block (8)
    const int i = tid & 31;          // particle slot

    if (i >= NIN && i < NP) {        // learned combos
        const int c = i - NIN;
        float4 x = make_float4(0.f, 0.f, 0.f, 0.f);
        #pragma unroll
        for (int j = 0; j < NIN; j++) {
            const float w = s_cola[c * NIN + j];
            const float4 xj = s_x[r][j];
            x.x += w * xj.x; x.y += w * xj.y; x.z += w * xj.z; x.w += w * xj.w;
        }
        s_x[r][i] = x;
    }
    __syncthreads();

    float m2 = 0.f, pt = 0.f;
    float4 xi = make_float4(0.f, 0.f, 0.f, 0.f);
    if (i < NP) {
        xi = s_x[r][i];
        m2 = xi.x * xi.x - xi.y * xi.y - xi.z * xi.z - xi.w * xi.w;
        pt = sqrtf(xi.y * xi.y + xi.z * xi.z);
        s_m2[r][i] = m2;
    }
    __syncthreads();
    if (i < NP) {
        float wesum = 0.f, wdsum = 0.f;
        for (int j = 0; j < NP; j++) {
            const float4 xj = s_x[r][j];                    // broadcast b128
            wesum += s_we[i * SW + j] * xj.x;               // conflict-free
            const float g = xi.x * xj.x - xi.y * xj.y - xi.z * xj.z - xi.w * xj.w;
            wdsum += s_wd[i * SW + j] * (m2 + s_m2[r][j] - 2.0f * g);
        }
        s_f[r * SF + i * 5 + 0] = m2;
        s_f[r * SF + i * 5 + 1] = pt;
        s_f[r * SF + i * 5 + 2] = xi.x;
        s_f[r * SF + i * 5 + 3] = wesum;
        s_f[r * SF + i * 5 + 4] = wdsum;
    }
    __syncthreads();

    // row-major write: fout[blk*RB + rr][c]
    for (int q = tid; q < RB * F; q += 256) {
        const int rr = q / F, c = q - rr * F;
        fout[(size_t)blk * RB * F + q] = s_f[rr * SF + c];
    }

    if (tid < F) {                   // per-block BN partials (deterministic)
        float s = 0.f, s2 = 0.f;
        #pragma unroll
        for (int rr = 0; rr < RB; rr++) {
            const float v = s_f[rr * SF + tid];
            s += v; s2 += v * v;
        }
        psum[(size_t)tid * NFEATBLK + blk] = s;
        psq [(size_t)tid * NFEATBLK + blk] = s2;
    }
}

// ---------------- BN reduce: partials -> per-feature scale/shift ----------------
template<int F>
__global__ __launch_bounds__(256) void bn_reduce(
    const float* __restrict__ psum, const float* __restrict__ psq,
    const float* __restrict__ gamma, const float* __restrict__ beta,
    float* __restrict__ bn)          // [2*F]: scale then shift
{
    __shared__ float s1[256], s2[256];
    const int f = blockIdx.x, tid = threadIdx.x;
    float a = 0.f, b = 0.f;
    for (int bk = tid; bk < NFEATBLK; bk += 256) {
        a += psum[(size_t)f * NFEATBLK + bk];
        b += psq [(size_t)f * NFEATBLK + bk];
    }
    s1[tid] = a; s2[tid] = b; __syncthreads();
    for (int s = 128; s > 0; s >>= 1) {
        if (tid < s) { s1[tid] += s1[tid + s]; s2[tid] += s2[tid + s]; }
        __syncthreads();
    }
    if (tid == 0) {
        const float mu  = s1[0] / (float)BATCH;
        const float var = s2[0] / (float)BATCH - mu * mu;
        const float sc  = gamma[f] * rsqrtf(var + 1e-5f);
        bn[f]     = sc;
        bn[F + f] = beta[f] - mu * sc;
    }
}

// ---------------- MLP kernel: BN affine + FC1(relu) + FC2 (+ top-6 select) ----------------
// RB=64 rows/block, lane = row. Wave w owns neurons [w*50, w*50+50): weight indices are
// wave-uniform -> s_load / SGPR operands; features per-lane in VGPRs (32 k's at a time).
template<int NF, int NOUT, bool SELECT>
__global__ __launch_bounds__(256, 3) void mlp_kernel(
    const float* __restrict__ fin,   // [B][NF] row-major
    const float* __restrict__ bn,    // [2*NF]
    const float* __restrict__ w1,    // [200][NF]
    const float* __restrict__ b1,    // [200]
    const float* __restrict__ w2,    // [NOUT][200]
    const float* __restrict__ b2,    // [NOUT]
    const float* __restrict__ vectors, // [B][10][4] (SELECT only)
    float* __restrict__ selout,      // [B][6][4]   (SELECT only)
    float* __restrict__ out,         // [B][21]
    int out_off)
{
    constexpr int RB = 64;
    // U dword stride: mult of 4 (b128 align); 164/148 give uniform bank coverage
    constexpr int SU = (NF == 160) ? 164 : 148;
    constexpr int NW = 50;           // neurons per wave
    constexpr int NKB = NF / 32;     // full 32-k blocks
    constexpr int REM = NF % 32;     // 0 (isr) or 12 (dec)
    __shared__ __align__(16) float U[RB * SU];   // features [row][k]; later: partials
    __shared__ __align__(16) float s_scale[NF], s_shift[NF];
    __shared__ float s_out[RB * 12];
    __shared__ int   s_idx[RB * 6];

    const int tid = threadIdx.x;
    const int blk = blockIdx.x;
    const int w = __builtin_amdgcn_readfirstlane(tid >> 6);  // wave id (uniform)
    const int r = tid & 63;                                  // lane = row

    for (int k = tid; k < NF; k += 256) { s_scale[k] = bn[k]; s_shift[k] = bn[NF + k]; }
    __syncthreads();

    // Phase A: coalesced float4 read of row-major features, BN affine, b128 LDS write.
    {
        constexpr int NF4 = NF / 4;
        const float4* fb4 = reinterpret_cast<const float4*>(fin + (size_t)blk * RB * NF);
        for (int q4 = tid; q4 < RB * NF4; q4 += 256) {
            const int row = q4 / NF4, c = (q4 - row * NF4) * 4;
            const float4 v = fb4[q4];
            const float4 sc = *reinterpret_cast<const float4*>(&s_scale[c]);
            const float4 sh = *reinterpret_cast<const float4*>(&s_shift[c]);
            float4 o;
            o.x = v.x * sc.x + sh.x; o.y = v.y * sc.y + sh.y;
            o.z = v.z * sc.z + sh.z; o.w = v.w * sc.w + sh.w;
            *reinterpret_cast<float4*>(&U[row * SU + c]) = o;
        }
    }
    __syncthreads();

    // FC1: acc2[j] (k-pair packed) over NF; weights via scalar pipe (uniform index).
    const float* frow = &U[r * SU];
    v2f acc2[NW];
    #pragma unroll
    for (int j = 0; j < NW; j++) acc2[j] = (v2f){0.f, 0.f};

    for (int kb = 0; kb < NKB; ++kb) {
        const int k0 = kb * 32;
        v2f f2[16];
        #pragma unroll
        for (int t = 0; t < 8; t++) {
            const float4 fa = *reinterpret_cast<const float4*>(&frow[k0 + 4 * t]);
            f2[2 * t]     = (v2f){fa.x, fa.y};
            f2[2 * t + 1] = (v2f){fa.z, fa.w};
        }
        #pragma unroll
        for (int j = 0; j < NW; j++) {
            const v2f* wp = reinterpret_cast<const v2f*>(
                w1 + (size_t)(w * NW + j) * NF + k0);        // uniform -> s_load
            #pragma unroll
            for (int p = 0; p < 16; p++) acc2[j] += wp[p] * f2[p];
        }
    }
    if (REM > 0) {                                           // NF=140 tail (12 k's)
        const int k0 = NKB * 32;
        v2f f2[REM > 0 ? REM / 2 : 1];
        #pragma unroll
        for (int t = 0; t < REM / 4; t++) {
            const float4 fa = *reinterpret_cast<const float4*>(&frow[k0 + 4 * t]);
            f2[2 * t]     = (v2f){fa.x, fa.y};
            f2[2 * t + 1] = (v2f){fa.z, fa.w};
        }
        #pragma unroll
        for (int j = 0; j < NW; j++) {
            const v2f* wp = reinterpret_cast<const v2f*>(
                w1 + (size_t)(w * NW + j) * NF + k0);
            #pragma unroll
            for (int p = 0; p < REM / 2; p++) acc2[j] += wp[p] * f2[p];
        }
    }
    __syncthreads();     // all waves done reading U -> safe to overlay partials

    // h (relu) -> packed neuron-pairs hp; FC2 partials per wave from registers.
    v2f hp[NW / 2];
    #pragma unroll
    for (int a = 0; a < NW / 2; a++) {
        const int n0 = w * NW + 2 * a;
        float h0 = acc2[2 * a][0] + acc2[2 * a][1] + b1[n0];
        float h1 = acc2[2 * a + 1][0] + acc2[2 * a + 1][1] + b1[n0 + 1];
        h0 = h0 > 0.f ? h0 : 0.f;
        h1 = h1 > 0.f ? h1 : 0.f;
        hp[a] = (v2f){h0, h1};
    }

    // FC2 partials: EVERY wave contributes its 50-neuron slice to EVERY output o.
    float* s_part = U;               // overlay: [4][RB][12] = 3072 floats << RB*SU
    for (int o = 0; o < NOUT; o++) {             // uniform per wave
        v2f a2 = (v2f){0.f, 0.f};
        const v2f* w2p = reinterpret_cast<const v2f*>(
            w2 + (size_t)o * FFDIM + w * NW);    // uniform -> s_load
        #pragma unroll
        for (int a = 0; a < NW / 2; a++) a2 += hp[a] * w2p[a];
        s_part[(w * RB + r) * 12 + o] = a2[0] + a2[1];
    }
    __syncthreads();

    // final reduce: out[row][o] = b2[o] + sum_w part
    for (int q = tid; q < RB * NOUT; q += 256) {
        const int row = q / NOUT, o = q - row * NOUT;
        float v = b2[o];
        #pragma unroll
        for (int ww = 0; ww < 4; ww++) v += s_part[(ww * RB + row) * 12 + o];
        s_out[row * 12 + o] = v;
    }
    __syncthreads();

    if (SELECT) {
        if (tid < RB) {              // per-row top-6 (ties -> lowest index), sorted asc
            float sc[10];
            #pragma unroll
            for (int o = 0; o < 10; o++) sc[o] = s_out[tid * 12 + o];
            bool used[10];
            #pragma unroll
            for (int o = 0; o < 10; o++) used[o] = false;
            int ids[6];
            for (int k = 0; k < 6; k++) {
                float m = -3.0e38f; int mi = 0;
                for (int o = 0; o < 10; o++)
                    if (!used[o] && sc[o] > m) { m = sc[o]; mi = o; }
                used[mi] = true; ids[k] = mi;
            }
            for (int a2i = 1; a2i < 6; a2i++) {  // insertion sort ascending
                const int v = ids[a2i]; int bp = a2i - 1;
                while (bp >= 0 && ids[bp] > v) { ids[bp + 1] = ids[bp]; bp--; }
                ids[bp + 1] = v;
            }
            #pragma unroll
            for (int k = 0; k < 6; k++) s_idx[tid * 6 + k] = ids[k];
        }
        __syncthreads();
        for (int q = tid; q < RB * 6; q += 256) {    // float4 gather of selected jets
            const int r2 = q / 6, j = q - r2 * 6;
            reinterpret_cast<float4*>(selout)[(size_t)blk * RB * 6 + q] =
                reinterpret_cast<const float4*>(vectors)
                    [(size_t)(blk * RB + r2) * NJ + s_idx[r2 * 6 + j]];
        }
    }

    for (int q = tid; q < RB * NOUT; q += 256) {
        const int r2 = q / NOUT, o = q - r2 * NOUT;
        out[(size_t)(blk * RB + r2) * OUTSTRIDE + out_off + o] = s_out[r2 * 12 + o];
    }
}

extern "C" void kernel_launch(void* const* d_in, const int* in_sizes, int n_in,
                              void* d_out, int out_size, void* d_ws, size_t ws_size,
                              hipStream_t stream) {
    const float* vectors  = (const float*)d_in[0];
    const float* isr_cola = (const float*)d_in[1];
    const float* isr_we   = (const float*)d_in[2];
    const float* isr_wd   = (const float*)d_in[3];
    const float* isr_bn_g = (const float*)d_in[4];
    const float* isr_bn_b = (const float*)d_in[5];
    const float* isr_w1   = (const float*)d_in[6];
    const float* isr_b1   = (const float*)d_in[7];
    const float* isr_w2   = (const float*)d_in[8];
    const float* isr_b2   = (const float*)d_in[9];
    const float* dec_cola = (const float*)d_in[10];
    const float* dec_we   = (const float*)d_in[11];
    const float* dec_wd   = (const float*)d_in[12];
    const float* dec_bn_g = (const float*)d_in[13];
    const float* dec_bn_b = (const float*)d_in[14];
    const float* dec_w1   = (const float*)d_in[15];
    const float* dec_b1   = (const float*)d_in[16];
    const float* dec_w2   = (const float*)d_in[17];
    const float* dec_b2   = (const float*)d_in[18];
    float* out = (float*)d_out;
    float* ws  = (float*)d_ws;

    // workspace layout (floats); f_buf reused by both heads (~29.4 MB total)
    float* f_buf  = ws;                    // 32768*160 = 5,242,880
    float* sel    = f_buf + 5242880;       // 32768*24 = 786,432
    float* ps     = sel + 786432;          // 160*4096 = 655,360
    float* pq     = ps + 655360;           // 655,360
    float* bn_i   = pq + 655360;           // 320
    float* bn_d   = bn_i + 320;            // 280

    feat_kernel<10, 32><<<4096, 256, 0, stream>>>(vectors, isr_cola, isr_we, isr_wd,
                                                  f_buf, ps, pq);
    bn_reduce<160><<<160, 256, 0, stream>>>(ps, pq, isr_bn_g, isr_bn_b, bn_i);
    mlp_kernel<160, 10, true><<<512, 256, 0, stream>>>(f_buf, bn_i, isr_w1, isr_b1,
                                                       isr_w2, isr_b2, vectors, sel,
                                                       out, 0);
    feat_kernel<6, 28><<<4096, 256, 0, stream>>>(sel, dec_cola, dec_we, dec_wd,
                                                 f_buf, ps, pq);
    bn_reduce<140><<<140, 256, 0, stream>>>(ps, pq, dec_bn_g, dec_bn_b, bn_d);
    mlp_kernel<140, 11, false><<<512, 256, 0, stream>>>(f_buf, bn_d, dec_w1, dec_b1,
                                                        dec_w2, dec_b2, nullptr, nullptr,
                                                        out, 10);
}

// Round 8
// 169.542 us; speedup vs baseline: 1.8194x; 1.8194x over previous
//
#include <hip/hip_runtime.h>

// Hydra_56633438765296: two-head LoLa/CoLa jet network, fp32 (no fp32 MFMA on CDNA4;
// rank-sensitive top-6 between heads keeps everything fp32 vector math).
// R7 post-mortem: acc2[50] didn't unroll -> runtime-indexed -> scratch (VGPR=72,
// VALUBusy 9%, 3x slowdown). R8: same lane=row / wave=neuron-slice / scalar-pipe-weights
// structure, but neuron groups of 18/16/16 via template<int G> (static unroll, acc fits
// registers); FC2 folded per-group as pk-FMA vs uniform w2; launch_bounds(256,2).

#define BATCH 32768
#define NJ 10
#define FFDIM 200
#define OUTSTRIDE 21
#define NFEATBLK 4096

typedef float v2f __attribute__((ext_vector_type(2)));

// ---------------- features kernel: cola + lola + BN partials ----------------
template<int NIN, int NP>
__global__ __launch_bounds__(256) void feat_kernel(
    const float* __restrict__ vin,    // [B][NIN][4]
    const float* __restrict__ cola,   // [22][NIN]
    const float* __restrict__ we,     // [NP][NP]
    const float* __restrict__ wd,     // [NP][NP]
    float* __restrict__ fout,         // [B][F] row-major
    float* __restrict__ psum,         // [F][4096]
    float* __restrict__ psq)          // [F][4096]
{
    constexpr int NC = 22;
    constexpr int F  = NP * 5;
    constexpr int RB = 8;             // rows per block
    constexpr int SW = NP + 1;        // odd stride -> conflict-free i-indexed reads
    constexpr int SF = F + 8;         // 2-way max on transposed readout
    __shared__ float s_cola[NC * NIN];
    __shared__ float s_we[NP * SW];
    __shared__ float s_wd[NP * SW];
    __shared__ float4 s_x[RB][NP];
    __shared__ float s_m2[RB][NP];
    __shared__ float s_f[RB * SF];

    const int tid = threadIdx.x;
    const int blk = blockIdx.x;

    for (int k = tid; k < NC * NIN; k += 256) s_cola[k] = cola[k];
    for (int k = tid; k < NP * NP; k += 256) {
        const int i2 = k / NP, j2 = k - i2 * NP;
        s_we[i2 * SW + j2] = we[k];
        s_wd[i2 * SW + j2] = wd[k];
    }
    for (int k = tid; k < RB * NIN * 4; k += 256)
        ((float*)&s_x[0][0])[(k / (NIN * 4)) * NP * 4 + (k % (NIN * 4))] =
            vin[(size_t)blk * RB * NIN * 4 + k];
    __syncthreads();

    const int r = tid >> 5;          // row in block (8)
    const int i = tid & 31;          // particle slot

    if (i >= NIN && i < NP) {        // learned combos
        const int c = i - NIN;
        float4 x = make_float4(0.f, 0.f, 0.f, 0.f);
        #pragma unroll
        for (int j = 0; j < NIN; j++) {
            const float w = s_cola[c * NIN + j];
            const float4 xj = s_x[r][j];
            x.x += w * xj.x; x.y += w * xj.y; x.z += w * xj.z; x.w += w * xj.w;
        }
        s_x[r][i] = x;
    }
    __syncthreads();

    float m2 = 0.f, pt = 0.f;
    float4 xi = make_float4(0.f, 0.f, 0.f, 0.f);
    if (i < NP) {
        xi = s_x[r][i];
        m2 = xi.x * xi.x - xi.y * xi.y - xi.z * xi.z - xi.w * xi.w;
        pt = sqrtf(xi.y * xi.y + xi.z * xi.z);
        s_m2[r][i] = m2;
    }
    __syncthreads();
    if (i < NP) {
        float wesum = 0.f, wdsum = 0.f;
        for (int j = 0; j < NP; j++) {
            const float4 xj = s_x[r][j];                    // broadcast b128
            wesum += s_we[i * SW + j] * xj.x;               // conflict-free
            const float g = xi.x * xj.x - xi.y * xj.y - xi.z * xj.z - xi.w * xj.w;
            wdsum += s_wd[i * SW + j] * (m2 + s_m2[r][j] - 2.0f * g);
        }
        s_f[r * SF + i * 5 + 0] = m2;
        s_f[r * SF + i * 5 + 1] = pt;
        s_f[r * SF + i * 5 + 2] = xi.x;
        s_f[r * SF + i * 5 + 3] = wesum;
        s_f[r * SF + i * 5 + 4] = wdsum;
    }
    __syncthreads();

    // row-major write: fout[blk*RB + rr][c]
    for (int q = tid; q < RB * F; q += 256) {
        const int rr = q / F, c = q - rr * F;
        fout[(size_t)blk * RB * F + q] = s_f[rr * SF + c];
    }

    if (tid < F) {                   // per-block BN partials (deterministic)
        float s = 0.f, s2 = 0.f;
        #pragma unroll
        for (int rr = 0; rr < RB; rr++) {
            const float v = s_f[rr * SF + tid];
            s += v; s2 += v * v;
        }
        psum[(size_t)tid * NFEATBLK + blk] = s;
        psq [(size_t)tid * NFEATBLK + blk] = s2;
    }
}

// ---------------- BN reduce: partials -> per-feature scale/shift ----------------
template<int F>
__global__ __launch_bounds__(256) void bn_reduce(
    const float* __restrict__ psum, const float* __restrict__ psq,
    const float* __restrict__ gamma, const float* __restrict__ beta,
    float* __restrict__ bn)          // [2*F]: scale then shift
{
    __shared__ float s1[256], s2[256];
    const int f = blockIdx.x, tid = threadIdx.x;
    float a = 0.f, b = 0.f;
    for (int bk = tid; bk < NFEATBLK; bk += 256) {
        a += psum[(size_t)f * NFEATBLK + bk];
        b += psq [(size_t)f * NFEATBLK + bk];
    }
    s1[tid] = a; s2[tid] = b; __syncthreads();
    for (int s = 128; s > 0; s >>= 1) {
        if (tid < s) { s1[tid] += s1[tid + s]; s2[tid] += s2[tid + s]; }
        __syncthreads();
    }
    if (tid == 0) {
        const float mu  = s1[0] / (float)BATCH;
        const float var = s2[0] / (float)BATCH - mu * mu;
        const float sc  = gamma[f] * rsqrtf(var + 1e-5f);
        bn[f]     = sc;
        bn[F + f] = beta[f] - mu * sc;
    }
}

// ---- FC1+FC2 neuron group: G neurons starting at uniform n0 (G even, <=18) ----
// acc[G] static-indexed (full unroll guaranteed by template G); weights via uniform
// s_load (scalar pipe); features from LDS once per k-chunk (1 ds_read_b128 : 2G pk-FMA).
template<int G, int NF, int NOUT>
__device__ __forceinline__ void do_group(
    const float* __restrict__ frow,   // &U[r*SU]
    const float* __restrict__ w1,
    const float* __restrict__ b1,
    const float* __restrict__ w2,
    int n0,                           // uniform (wave-level) first neuron
    v2f* __restrict__ part2)          // [NOUT] per-thread packed partials
{
    v2f acc[G];
    #pragma unroll
    for (int j = 0; j < G; j++) acc[j] = (v2f){0.f, 0.f};

    for (int kc = 0; kc < NF / 4; kc++) {        // rolled k-loop (acc static)
        const float4 fa = *reinterpret_cast<const float4*>(&frow[kc * 4]);
        const v2f f01 = (v2f){fa.x, fa.y}, f23 = (v2f){fa.z, fa.w};
        #pragma unroll
        for (int j = 0; j < G; j++) {
            const float4 wv = *reinterpret_cast<const float4*>(
                w1 + (size_t)(n0 + j) * NF + kc * 4);        // uniform -> s_load
            acc[j] += (v2f){wv.x, wv.y} * f01;
            acc[j] += (v2f){wv.z, wv.w} * f23;
        }
    }
    #pragma unroll
    for (int a = 0; a < G / 2; a++) {            // relu + FC2 partial (packed pairs)
        float h0 = acc[2 * a][0] + acc[2 * a][1] + b1[n0 + 2 * a];
        float h1 = acc[2 * a + 1][0] + acc[2 * a + 1][1] + b1[n0 + 2 * a + 1];
        h0 = h0 > 0.f ? h0 : 0.f;
        h1 = h1 > 0.f ? h1 : 0.f;
        const v2f hp = (v2f){h0, h1};
        #pragma unroll
        for (int o = 0; o < NOUT; o++) {
            const v2f w2v = *reinterpret_cast<const v2f*>(
                w2 + (size_t)o * FFDIM + n0 + 2 * a);        // uniform -> s_load
            part2[o] += hp * w2v;
        }
    }
}

// ---------------- MLP kernel: BN affine + FC1(relu) + FC2 (+ top-6 select) ----------------
// RB=64 rows/block, lane=row, wave w owns neurons [50w,50w+50) in groups 18/16/16.
template<int NF, int NOUT, bool SELECT>
__global__ __launch_bounds__(256, 2) void mlp_kernel(
    const float* __restrict__ fin,   // [B][NF] row-major
    const float* __restrict__ bn,    // [2*NF]
    const float* __restrict__ w1,    // [200][NF]
    const float* __restrict__ b1,    // [200]
    const float* __restrict__ w2,    // [NOUT][200]
    const float* __restrict__ b2,    // [NOUT]
    const float* __restrict__ vectors, // [B][10][4] (SELECT only)
    float* __restrict__ selout,      // [B][6][4]   (SELECT only)
    float* __restrict__ out,         // [B][21]
    int out_off)
{
    constexpr int RB = 64;
    constexpr int SU = (NF == 160) ? 164 : 148;  // 4-dword aligned; lane-bank stride
    __shared__ __align__(16) float U[RB * SU];   // features [row][k]; later: partials
    __shared__ __align__(16) float s_scale[NF], s_shift[NF];
    __shared__ float s_out[RB * 12];
    __shared__ int   s_idx[RB * 6];

    const int tid = threadIdx.x;
    const int blk = blockIdx.x;
    const int w = __builtin_amdgcn_readfirstlane(tid >> 6);  // wave id (uniform)
    const int r = tid & 63;                                  // lane = row

    for (int k = tid; k < NF; k += 256) { s_scale[k] = bn[k]; s_shift[k] = bn[NF + k]; }
    __syncthreads();

    // Phase A: coalesced float4 read of row-major features, BN affine, b128 LDS write.
    {
        constexpr int NF4 = NF / 4;
        const float4* fb4 = reinterpret_cast<const float4*>(fin + (size_t)blk * RB * NF);
        for (int q4 = tid; q4 < RB * NF4; q4 += 256) {
            const int row = q4 / NF4, c = (q4 - row * NF4) * 4;
            const float4 v = fb4[q4];
            const float4 sc = *reinterpret_cast<const float4*>(&s_scale[c]);
            const float4 sh = *reinterpret_cast<const float4*>(&s_shift[c]);
            float4 o;
            o.x = v.x * sc.x + sh.x; o.y = v.y * sc.y + sh.y;
            o.z = v.z * sc.z + sh.z; o.w = v.w * sc.w + sh.w;
            *reinterpret_cast<float4*>(&U[row * SU + c]) = o;
        }
    }
    __syncthreads();

    // FC1 + FC2 partials in register-sized neuron groups (18/16/16 per wave).
    const float* frow = &U[r * SU];
    const int n0 = w * 50;
    v2f part2[NOUT];
    #pragma unroll
    for (int o = 0; o < NOUT; o++) part2[o] = (v2f){0.f, 0.f};

    do_group<18, NF, NOUT>(frow, w1, b1, w2, n0,      part2);
    do_group<16, NF, NOUT>(frow, w1, b1, w2, n0 + 18, part2);
    do_group<16, NF, NOUT>(frow, w1, b1, w2, n0 + 34, part2);
    __syncthreads();     // all waves done reading U -> safe to overlay partials

    float* s_part = U;               // overlay: [4][RB][12] = 3072 floats << RB*SU
    #pragma unroll
    for (int o = 0; o < NOUT; o++)
        s_part[(w * RB + r) * 12 + o] = part2[o][0] + part2[o][1];
    __syncthreads();

    // final reduce: out[row][o] = b2[o] + sum_w part
    for (int q = tid; q < RB * NOUT; q += 256) {
        const int row = q / NOUT, o = q - row * NOUT;
        float v = b2[o];
        #pragma unroll
        for (int ww = 0; ww < 4; ww++) v += s_part[(ww * RB + row) * 12 + o];
        s_out[row * 12 + o] = v;
    }
    __syncthreads();

    if (SELECT) {
        if (tid < RB) {              // per-row top-6 (ties -> lowest index), sorted asc
            float sc[10];
            #pragma unroll
            for (int o = 0; o < 10; o++) sc[o] = s_out[tid * 12 + o];
            bool used[10];
            #pragma unroll
            for (int o = 0; o < 10; o++) used[o] = false;
            int ids[6];
            for (int k = 0; k < 6; k++) {
                float m = -3.0e38f; int mi = 0;
                for (int o = 0; o < 10; o++)
                    if (!used[o] && sc[o] > m) { m = sc[o]; mi = o; }
                used[mi] = true; ids[k] = mi;
            }
            for (int a2i = 1; a2i < 6; a2i++) {  // insertion sort ascending
                const int v = ids[a2i]; int bp = a2i - 1;
                while (bp >= 0 && ids[bp] > v) { ids[bp + 1] = ids[bp]; bp--; }
                ids[bp + 1] = v;
            }
            #pragma unroll
            for (int k = 0; k < 6; k++) s_idx[tid * 6 + k] = ids[k];
        }
        __syncthreads();
        for (int q = tid; q < RB * 6; q += 256) {    // float4 gather of selected jets
            const int r2 = q / 6, j = q - r2 * 6;
            reinterpret_cast<float4*>(selout)[(size_t)blk * RB * 6 + q] =
                reinterpret_cast<const float4*>(vectors)
                    [(size_t)(blk * RB + r2) * NJ + s_idx[r2 * 6 + j]];
        }
    }

    for (int q = tid; q < RB * NOUT; q += 256) {
        const int r2 = q / NOUT, o = q - r2 * NOUT;
        out[(size_t)(blk * RB + r2) * OUTSTRIDE + out_off + o] = s_out[r2 * 12 + o];
    }
}

extern "C" void kernel_launch(void* const* d_in, const int* in_sizes, int n_in,
                              void* d_out, int out_size, void* d_ws, size_t ws_size,
                              hipStream_t stream) {
    const float* vectors  = (const float*)d_in[0];
    const float* isr_cola = (const float*)d_in[1];
    const float* isr_we   = (const float*)d_in[2];
    const float* isr_wd   = (const float*)d_in[3];
    const float* isr_bn_g = (const float*)d_in[4];
    const float* isr_bn_b = (const float*)d_in[5];
    const float* isr_w1   = (const float*)d_in[6];
    const float* isr_b1   = (const float*)d_in[7];
    const float* isr_w2   = (const float*)d_in[8];
    const float* isr_b2   = (const float*)d_in[9];
    const float* dec_cola = (const float*)d_in[10];
    const float* dec_we   = (const float*)d_in[11];
    const float* dec_wd   = (const float*)d_in[12];
    const float* dec_bn_g = (const float*)d_in[13];
    const float* dec_bn_b = (const float*)d_in[14];
    const float* dec_w1   = (const float*)d_in[15];
    const float* dec_b1   = (const float*)d_in[16];
    const float* dec_w2   = (const float*)d_in[17];
    const float* dec_b2   = (const float*)d_in[18];
    float* out = (float*)d_out;
    float* ws  = (float*)d_ws;

    // workspace layout (floats); f_buf reused by both heads (~29.4 MB total)
    float* f_buf  = ws;                    // 32768*160 = 5,242,880
    float* sel    = f_buf + 5242880;       // 32768*24 = 786,432
    float* ps     = sel + 786432;          // 160*4096 = 655,360
    float* pq     = ps + 655360;           // 655,360
    float* bn_i   = pq + 655360;           // 320
    float* bn_d   = bn_i + 320;            // 280

    feat_kernel<10, 32><<<4096, 256, 0, stream>>>(vectors, isr_cola, isr_we, isr_wd,
                                                  f_buf, ps, pq);
    bn_reduce<160><<<160, 256, 0, stream>>>(ps, pq, isr_bn_g, isr_bn_b, bn_i);
    mlp_kernel<160, 10, true><<<512, 256, 0, stream>>>(f_buf, bn_i, isr_w1, isr_b1,
                                                       isr_w2, isr_b2, vectors, sel,
                                                       out, 0);
    feat_kernel<6, 28><<<4096, 256, 0, stream>>>(sel, dec_cola, dec_we, dec_wd,
                                                 f_buf, ps, pq);
    bn_reduce<140><<<140, 256, 0, stream>>>(ps, pq, dec_bn_g, dec_bn_b, bn_d);
    mlp_kernel<140, 11, false><<<512, 256, 0, stream>>>(f_buf, bn_d, dec_w1, dec_b1,
                                                        dec_w2, dec_b2, nullptr, nullptr,
                                                        out, 10);
}

// Round 9
// 156.504 us; speedup vs baseline: 1.9710x; 1.0833x over previous
//
#include <hip/hip_runtime.h>

// Hydra_56633438765296: two-head LoLa/CoLa jet network, fp32 (no fp32 MFMA on CDNA4;
// rank-sensitive top-6 between heads keeps everything fp32 vector math).
// R8 post-mortem: scalar-pipe weights hit SGPR budget (no prefetch possible) + K$
// thrash -> serialization (VALU 23%). Ledger R4-R8: fp32 GEMM is bound by the shared
// per-CU pipe feeding FMAs. R9: maximize FMA per LDS instr -- thread = 8 rows x 7
// neurons (112 pk-FMA per 15 ds_read_b128, 2.5x R5's ratio), LDS-staged weight tiles
// (dbuf), U/H LDS union (62.5KB -> 2 blocks/CU), Phase C with b128 h-reads reused
// across 3 wave-uniform outputs (w2 on scalar pipe, K$-resident).

#define BATCH 32768
#define NJ 10
#define FFDIM 200
#define OUTSTRIDE 21
#define NFEATBLK 4096

typedef float v2f __attribute__((ext_vector_type(2)));

// ---------------- features kernel: cola + lola + BN partials ----------------
template<int NIN, int NP>
__global__ __launch_bounds__(256) void feat_kernel(
    const float* __restrict__ vin,    // [B][NIN][4]
    const float* __restrict__ cola,   // [22][NIN]
    const float* __restrict__ we,     // [NP][NP]
    const float* __restrict__ wd,     // [NP][NP]
    float* __restrict__ fout,         // [B][F] row-major
    float* __restrict__ psum,         // [F][4096]
    float* __restrict__ psq)          // [F][4096]
{
    constexpr int NC = 22;
    constexpr int F  = NP * 5;
    constexpr int RB = 8;             // rows per block
    constexpr int SW = NP + 1;        // odd stride -> conflict-free i-indexed reads
    constexpr int SF = F + 8;         // 2-way max on transposed readout
    __shared__ float s_cola[NC * NIN];
    __shared__ float s_we[NP * SW];
    __shared__ float s_wd[NP * SW];
    __shared__ float4 s_x[RB][NP];
    __shared__ float s_m2[RB][NP];
    __shared__ float s_f[RB * SF];

    const int tid = threadIdx.x;
    const int blk = blockIdx.x;

    for (int k = tid; k < NC * NIN; k += 256) s_cola[k] = cola[k];
    for (int k = tid; k < NP * NP; k += 256) {
        const int i2 = k / NP, j2 = k - i2 * NP;
        s_we[i2 * SW + j2] = we[k];
        s_wd[i2 * SW + j2] = wd[k];
    }
    for (int k = tid; k < RB * NIN * 4; k += 256)
        ((float*)&s_x[0][0])[(k / (NIN * 4)) * NP * 4 + (k % (NIN * 4))] =
            vin[(size_t)blk * RB * NIN * 4 + k];
    __syncthreads();

    const int r = tid >> 5;          // row in block (8)
    const int i = tid & 31;          // particle slot

    if (i >= NIN && i < NP) {        // learned combos
        const int c = i - NIN;
        float4 x = make_float4(0.f, 0.f, 0.f, 0.f);
        #pragma unroll
        for (int j = 0; j < NIN; j++) {
            const float w = s_cola[c * NIN + j];
            const float4 xj = s_x[r][j];
            x.x += w * xj.x; x.y += w * xj.y; x.z += w * xj.z; x.w += w * xj.w;
        }
        s_x[r][i] = x;
    }
    __syncthreads();

    float m2 = 0.f, pt = 0.f;
    float4 xi = make_float4(0.f, 0.f, 0.f, 0.f);
    if (i < NP) {
        xi = s_x[r][i];
        m2 = xi.x * xi.x - xi.y * xi.y - xi.z * xi.z - xi.w * xi.w;
        pt = sqrtf(xi.y * xi.y + xi.z * xi.z);
        s_m2[r][i] = m2;
    }
    __syncthreads();
    if (i < NP) {
        float wesum = 0.f, wdsum = 0.f;
        for (int j = 0; j < NP; j++) {
            const float4 xj = s_x[r][j];                    // broadcast b128
            wesum += s_we[i * SW + j] * xj.x;               // conflict-free
            const float g = xi.x * xj.x - xi.y * xj.y - xi.z * xj.z - xi.w * xj.w;
            wdsum += s_wd[i * SW + j] * (m2 + s_m2[r][j] - 2.0f * g);
        }
        s_f[r * SF + i * 5 + 0] = m2;
        s_f[r * SF + i * 5 + 1] = pt;
        s_f[r * SF + i * 5 + 2] = xi.x;
        s_f[r * SF + i * 5 + 3] = wesum;
        s_f[r * SF + i * 5 + 4] = wdsum;
    }
    __syncthreads();

    // row-major write: fout[blk*RB + rr][c]
    for (int q = tid; q < RB * F; q += 256) {
        const int rr = q / F, c = q - rr * F;
        fout[(size_t)blk * RB * F + q] = s_f[rr * SF + c];
    }

    if (tid < F) {                   // per-block BN partials (deterministic)
        float s = 0.f, s2 = 0.f;
        #pragma unroll
        for (int rr = 0; rr < RB; rr++) {
            const float v = s_f[rr * SF + tid];
            s += v; s2 += v * v;
        }
        psum[(size_t)tid * NFEATBLK + blk] = s;
        psq [(size_t)tid * NFEATBLK + blk] = s2;
    }
}

// ---------------- BN reduce: partials -> per-feature scale/shift ----------------
template<int F>
__global__ __launch_bounds__(256) void bn_reduce(
    const float* __restrict__ psum, const float* __restrict__ psq,
    const float* __restrict__ gamma, const float* __restrict__ beta,
    float* __restrict__ bn)          // [2*F]: scale then shift
{
    __shared__ float s1[256], s2[256];
    const int f = blockIdx.x, tid = threadIdx.x;
    float a = 0.f, b = 0.f;
    for (int bk = tid; bk < NFEATBLK; bk += 256) {
        a += psum[(size_t)f * NFEATBLK + bk];
        b += psq [(size_t)f * NFEATBLK + bk];
    }
    s1[tid] = a; s2[tid] = b; __syncthreads();
    for (int s = 128; s > 0; s >>= 1) {
        if (tid < s) { s1[tid] += s1[tid + s]; s2[tid] += s2[tid + s]; }
        __syncthreads();
    }
    if (tid == 0) {
        const float mu  = s1[0] / (float)BATCH;
        const float var = s2[0] / (float)BATCH - mu * mu;
        const float sc  = gamma[f] * rsqrtf(var + 1e-5f);
        bn[f]     = sc;
        bn[F + f] = beta[f] - mu * sc;
    }
}

// ---------------- MLP kernel: BN affine + FC1(relu) + FC2 (+ top-6 select) ----------------
// RB=64 rows. Thread = 8 rows x 7 neurons (rowgroup = tid&7, ngroup = tid>>3; neurons
// padded to 224 -> exactly 256 threads). Per 4-k chunk: 8 f-b128 + 7 w-b128 feed
// 112 pk-FMA. Weights staged in LDS (double-buffered, one barrier/chunk).
// LDS union: UH holds U[64][SU] (features) then H[64][204] (hidden).
template<int NF, int NOUT, bool SELECT>
__global__ __launch_bounds__(256, 2) void mlp_kernel(
    const float* __restrict__ fin,   // [B][NF] row-major
    const float* __restrict__ bn,    // [2*NF]
    const float* __restrict__ w1,    // [200][NF]
    const float* __restrict__ b1,    // [200]
    const float* __restrict__ w2,    // [NOUT][200]
    const float* __restrict__ b2,    // [NOUT]
    const float* __restrict__ vectors, // [B][10][4] (SELECT only)
    float* __restrict__ selout,      // [B][6][4]   (SELECT only)
    float* __restrict__ out,         // [B][21]
    int out_off)
{
    constexpr int RB  = 64;
    constexpr int SU  = (NF == 160) ? 164 : 148;  // U stride: 16B-aligned, 8 bank slots
    constexpr int SH  = 204;                       // H stride: 16B-aligned, 8 bank slots
    constexpr int NCH = NF / 4;                    // k-chunks
    __shared__ __align__(16) float UH[RB * SH];    // 52.2KB: U then H (union)
    __shared__ __align__(16) float s_w[2][224 * 4];// 7.2KB weight tiles (dbuf)
    __shared__ float s_out[RB * 12];
    __shared__ int   s_idx[RB * 6];

    const int tid = threadIdx.x;
    const int blk = blockIdx.x;
    float* s_scale = &UH[RB * SU];   // scale/shift live in the UH tail (dead after A)
    float* s_shift = s_scale + NF;

    // prologue: first weight tile -> regs; scale/shift -> LDS tail
    const int wrow = (tid < 200) ? tid : 199;      // rows 200-223 duplicate row 199
    float4 wv;
    if (tid < 224) wv = *reinterpret_cast<const float4*>(w1 + (size_t)wrow * NF);
    for (int k = tid; k < NF; k += 256) { s_scale[k] = bn[k]; s_shift[k] = bn[NF + k]; }
    __syncthreads();

    // Phase A: coalesced float4 feature read, BN affine, U[row][k] write.
    {
        constexpr int NF4 = NF / 4;
        const float4* fb4 = reinterpret_cast<const float4*>(fin + (size_t)blk * RB * NF);
        for (int q4 = tid; q4 < RB * NF4; q4 += 256) {
            const int row = q4 / NF4, c = (q4 - row * NF4) * 4;
            const float4 v = fb4[q4];
            float4 o;
            o.x = v.x * s_scale[c + 0] + s_shift[c + 0];
            o.y = v.y * s_scale[c + 1] + s_shift[c + 1];
            o.z = v.z * s_scale[c + 2] + s_shift[c + 2];
            o.w = v.w * s_scale[c + 3] + s_shift[c + 3];
            *reinterpret_cast<float4*>(&UH[row * SU + c]) = o;
        }
    }
    if (tid < 224) {
        *reinterpret_cast<float4*>(&s_w[0][tid * 4]) = wv;   // stage tile 0
        wv = *reinterpret_cast<const float4*>(w1 + (size_t)wrow * NF + 4);  // tile 1
    }
    __syncthreads();                 // U + s_w[0] ready

    // FC1: acc[7 neurons][8 rows] (v2f k-pair partials).
    const int rg = tid & 7;          // rowgroup: rows rg*8 .. rg*8+7
    const int ng = tid >> 3;         // ngroup:   neurons ng*7 .. ng*7+6 (<224)
    v2f acc[7][8];
    #pragma unroll
    for (int j = 0; j < 7; j++)
        #pragma unroll
        for (int i = 0; i < 8; i++) acc[j][i] = (v2f){0.f, 0.f};

    for (int kt = 0; kt < NCH; kt++) {
        const int b = kt & 1;
        float4 wq[7], fq[8];
        #pragma unroll
        for (int j = 0; j < 7; j++)      // 8 distinct addrs/wave -> 8 slots, no conflict
            wq[j] = *reinterpret_cast<const float4*>(&s_w[b][(ng * 7 + j) * 4]);
        #pragma unroll
        for (int i = 0; i < 8; i++)      // 8 distinct rows/wave -> 8 slots, no conflict
            fq[i] = *reinterpret_cast<const float4*>(&UH[(rg * 8 + i) * SU + kt * 4]);
        #pragma unroll
        for (int j = 0; j < 7; j++) {
            const v2f wlo = (v2f){wq[j].x, wq[j].y};
            const v2f whi = (v2f){wq[j].z, wq[j].w};
            #pragma unroll
            for (int i = 0; i < 8; i++) {
                acc[j][i] += wlo * (v2f){fq[i].x, fq[i].y};
                acc[j][i] += whi * (v2f){fq[i].z, fq[i].w};
            }
        }
        if (tid < 224 && kt + 1 < NCH) {
            *reinterpret_cast<float4*>(&s_w[b ^ 1][tid * 4]) = wv;  // stage kt+1
            const int kn = (kt + 2 < NCH) ? (kt + 2) * 4 : (NCH - 1) * 4;
            wv = *reinterpret_cast<const float4*>(w1 + (size_t)wrow * NF + kn);
        }
        __syncthreads();
    }

    // H-write (UH reused as H[row][SH]; U dead -- final chunk barrier passed).
    #pragma unroll
    for (int j = 0; j < 7; j++) {
        const int n = ng * 7 + j;
        if (n < 200) {
            const float bb = b1[n];
            #pragma unroll
            for (int i = 0; i < 8; i++) {
                const float h = acc[j][i][0] + acc[j][i][1] + bb;
                UH[(rg * 8 + i) * SH + n] = h > 0.f ? h : 0.f;
            }
        }
    }
    __syncthreads();

    // Phase C: lane = row; wave w handles outputs {w, w+4, w+8} (uniform -> s_load w2).
    const int w = __builtin_amdgcn_readfirstlane(tid >> 6);
    const int r = tid & 63;
    {
        v2f a2[3];
        #pragma unroll
        for (int m = 0; m < 3; m++) a2[m] = (v2f){0.f, 0.f};
        for (int kc = 0; kc < FFDIM / 4; kc++) {
            const float4 hv = *reinterpret_cast<const float4*>(&UH[r * SH + kc * 4]);
            const v2f hlo = (v2f){hv.x, hv.y}, hhi = (v2f){hv.z, hv.w};
            #pragma unroll
            for (int m = 0; m < 3; m++) {
                const int o = w + 4 * m;
                if (o < NOUT) {
                    const float4 w2v = *reinterpret_cast<const float4*>(
                        w2 + (size_t)o * FFDIM + kc * 4);
                    a2[m] += (v2f){w2v.x, w2v.y} * hlo;
                    a2[m] += (v2f){w2v.z, w2v.w} * hhi;
                }
            }
        }
        #pragma unroll
        for (int m = 0; m < 3; m++) {
            const int o = w + 4 * m;
            if (o < NOUT) s_out[r * 12 + o] = a2[m][0] + a2[m][1] + b2[o];
        }
    }
    __syncthreads();

    if (SELECT) {
        if (tid < RB) {              // per-row top-6 (ties -> lowest index), sorted asc
            float sc[10];
            #pragma unroll
            for (int o = 0; o < 10; o++) sc[o] = s_out[tid * 12 + o];
            bool used[10];
            #pragma unroll
            for (int o = 0; o < 10; o++) used[o] = false;
            int ids[6];
            for (int k = 0; k < 6; k++) {
                float m = -3.0e38f; int mi = 0;
                for (int o = 0; o < 10; o++)
                    if (!used[o] && sc[o] > m) { m = sc[o]; mi = o; }
                used[mi] = true; ids[k] = mi;
            }
            for (int a2i = 1; a2i < 6; a2i++) {  // insertion sort ascending
                const int v = ids[a2i]; int bp = a2i - 1;
                while (bp >= 0 && ids[bp] > v) { ids[bp + 1] = ids[bp]; bp--; }
                ids[bp + 1] = v;
            }
            #pragma unroll
            for (int k = 0; k < 6; k++) s_idx[tid * 6 + k] = ids[k];
        }
        __syncthreads();
        for (int q = tid; q < RB * 6; q += 256) {    // float4 gather of selected jets
            const int r2 = q / 6, j = q - r2 * 6;
            reinterpret_cast<float4*>(selout)[(size_t)blk * RB * 6 + q] =
                reinterpret_cast<const float4*>(vectors)
                    [(size_t)(blk * RB + r2) * NJ + s_idx[r2 * 6 + j]];
        }
    }

    for (int q = tid; q < RB * NOUT; q += 256) {
        const int r2 = q / NOUT, o = q - r2 * NOUT;
        out[(size_t)(blk * RB + r2) * OUTSTRIDE + out_off + o] = s_out[r2 * 12 + o];
    }
}

extern "C" void kernel_launch(void* const* d_in, const int* in_sizes, int n_in,
                              void* d_out, int out_size, void* d_ws, size_t ws_size,
                              hipStream_t stream) {
    const float* vectors  = (const float*)d_in[0];
    const float* isr_cola = (const float*)d_in[1];
    const float* isr_we   = (const float*)d_in[2];
    const float* isr_wd   = (const float*)d_in[3];
    const float* isr_bn_g = (const float*)d_in[4];
    const float* isr_bn_b = (const float*)d_in[5];
    const float* isr_w1   = (const float*)d_in[6];
    const float* isr_b1   = (const float*)d_in[7];
    const float* isr_w2   = (const float*)d_in[8];
    const float* isr_b2   = (const float*)d_in[9];
    const float* dec_cola = (const float*)d_in[10];
    const float* dec_we   = (const float*)d_in[11];
    const float* dec_wd   = (const float*)d_in[12];
    const float* dec_bn_g = (const float*)d_in[13];
    const float* dec_bn_b = (const float*)d_in[14];
    const float* dec_w1   = (const float*)d_in[15];
    const float* dec_b1   = (const float*)d_in[16];
    const float* dec_w2   = (const float*)d_in[17];
    const float* dec_b2   = (const float*)d_in[18];
    float* out = (float*)d_out;
    float* ws  = (float*)d_ws;

    // workspace layout (floats); f_buf reused by both heads (~29.4 MB total)
    float* f_buf  = ws;                    // 32768*160 = 5,242,880
    float* sel    = f_buf + 5242880;       // 32768*24 = 786,432
    float* ps     = sel + 786432;          // 160*4096 = 655,360
    float* pq     = ps + 655360;           // 655,360
    float* bn_i   = pq + 655360;           // 320
    float* bn_d   = bn_i + 320;            // 280

    feat_kernel<10, 32><<<4096, 256, 0, stream>>>(vectors, isr_cola, isr_we, isr_wd,
                                                  f_buf, ps, pq);
    bn_reduce<160><<<160, 256, 0, stream>>>(ps, pq, isr_bn_g, isr_bn_b, bn_i);
    mlp_kernel<160, 10, true><<<512, 256, 0, stream>>>(f_buf, bn_i, isr_w1, isr_b1,
                                                       isr_w2, isr_b2, vectors, sel,
                                                       out, 0);
    feat_kernel<6, 28><<<4096, 256, 0, stream>>>(sel, dec_cola, dec_we, dec_wd,
                                                 f_buf, ps, pq);
    bn_reduce<140><<<140, 256, 0, stream>>>(ps, pq, dec_bn_g, dec_bn_b, bn_d);
    mlp_kernel<140, 11, false><<<512, 256, 0, stream>>>(f_buf, bn_d, dec_w1, dec_b1,
                                                        dec_w2, dec_b2, nullptr, nullptr,
                                                        out, 10);
}